// Round 6
// baseline (746.617 us; speedup 1.0000x reference)
//
#include <hip/hip_runtime.h>

#define L_SEQ 8192
#define DIMN  2048
#define CHUNK 32
#define NCHUNK (L_SEQ / CHUNK)   // 256 chunks
#define NSCAN  (2 * NCHUNK)      // 512 scan blocks (chunk x channel-half)
#define NWCONV (DIMN * DIMN / 4 / 256)  // 4096 wconv blocks

typedef float  f32x4  __attribute__((ext_vector_type(4)));
typedef __bf16 bf16x8 __attribute__((ext_vector_type(8)));

__device__ __forceinline__ unsigned short f2bf(float f) {
    unsigned int u = __float_as_uint(f);
    u += 0x7fffu + ((u >> 16) & 1u);          // round-to-nearest-even
    return (unsigned short)(u >> 16);
}

__device__ __forceinline__ float sigmoidf_(float v) {
    return 1.0f / (1.0f + __expf(-v));
}

// ---- flag reset (graph replays: flags must be re-zeroed every iteration) ----
__global__ void zeroflags(unsigned int* __restrict__ flags) {
    flags[threadIdx.x * 2]     = 0u;
    flags[threadIdx.x * 2 + 1] = 0u;
}

// ---- Single-pass scan with decoupled lookback + fused W convert ----
// Blocks 0..511: chunk c = b>>1, channel-half cg = b&1 (channels independent
// across cg, so flags/carries are per (c,cg)).
//   1. local scan of chunk c with h_in=0, ALL 32 values kept in VGPRs (128)
//   2. publish carry (= last local) + release-flag  (syncthreads drains vmcnt,
//      tid0: threadfence -> agent atomic store)
//   3. h_in = xml chained over predecessors' carries (16-wide batches; spin on
//      flags with agent-acquire loads; threadfence before carry reads so
//      graph-replay-stale L2 lines are invalidated)
//   4. emit x_mix[t] = bf16(loc[t] + f^(t+1) * h_in)   [linearity of the EMA]
// => x is read ONCE (was twice), no separate prefix kernel, no rescan.
// Deadlock-free: block (c,cg) waits only on (j<c,cg); waiting blocks are either
// co-resident (512 blocks ~2/CU) or behind retiring wconv blocks.
// Blocks 512..4607: W fp32->bf16 (independent, retire unconditionally).
__global__ __launch_bounds__(256) void scan1p(
        const float* __restrict__ x, const float* __restrict__ fp,
        const float* __restrict__ xml, const float* __restrict__ W,
        float* __restrict__ carry, unsigned int* __restrict__ flags,
        unsigned short* __restrict__ xmix, unsigned short* __restrict__ Wb) {
    const int b   = blockIdx.x;
    const int tid = threadIdx.x;

    if (b >= NSCAN) {                          // ---- W convert ----
        int i = (b - NSCAN) * 256 + tid;       // float4 index into W
        float4 v = ((const float4*)W)[i];
        ushort4 o;
        o.x = f2bf(v.x); o.y = f2bf(v.y); o.z = f2bf(v.z); o.w = f2bf(v.w);
        ((ushort4*)Wb)[i] = o;
        return;
    }

    const int cg = b & 1;
    const int c  = b >> 1;
    const int d4 = cg * 256 + tid;             // float4 channel index
    float4 f4 = ((const float4*)fp)[d4];
    float fa = sigmoidf_(f4.x), fb = sigmoidf_(f4.y),
          fc = sigmoidf_(f4.z), fd = sigmoidf_(f4.w);
    float ga = 1.f - fa, gb = 1.f - fb, gc = 1.f - fc, gd = 1.f - fd;

    // 1. local scan, locals kept in registers (static indices: stays in VGPRs)
    f32x4 loc[CHUNK];
    const float4* xp = (const float4*)(x + (size_t)c * CHUNK * DIMN) + d4;
    {
        float ha = 0.f, hb = 0.f, hc = 0.f, hd = 0.f;
#pragma unroll
        for (int t = 0; t < CHUNK; ++t) {
            float4 v = xp[(size_t)t * (DIMN / 4)];
            ha = fmaf(fa, ha, ga * v.x);
            hb = fmaf(fb, hb, gb * v.y);
            hc = fmaf(fc, hc, gc * v.z);
            hd = fmaf(fd, hd, gd * v.w);
            loc[t] = (f32x4){ha, hb, hc, hd};
        }
        // 2. publish carry + flag
        ((float4*)(carry + (size_t)c * DIMN))[d4] = (float4){ha, hb, hc, hd};
    }
    __syncthreads();                           // drains vmcnt of all waves
    if (tid == 0) {
        __threadfence();                       // writeback L2 -> device scope
        __hip_atomic_store(&flags[c * 2 + cg], 1u,
                           __ATOMIC_RELEASE, __HIP_MEMORY_SCOPE_AGENT);
    }

    // 3. h_in via lookback chain (same fma chain as the proven prefix kernels)
    float Fa = fa, Fb = fb, Fc = fc, Fd = fd;  // f^CHUNK via 5 squarings
    Fa *= Fa; Fa *= Fa; Fa *= Fa; Fa *= Fa; Fa *= Fa;
    Fb *= Fb; Fb *= Fb; Fb *= Fb; Fb *= Fb; Fb *= Fb;
    Fc *= Fc; Fc *= Fc; Fc *= Fc; Fc *= Fc; Fc *= Fc;
    Fd *= Fd; Fd *= Fd; Fd *= Fd; Fd *= Fd; Fd *= Fd;
    float4 m4 = ((const float4*)xml)[d4];
    float ha = m4.x, hb = m4.y, hc = m4.z, hd = m4.w;
    for (int j0 = 0; j0 < c; j0 += 16) {
        int nb = c - j0; if (nb > 16) nb = 16;
        if (tid < nb) {
            while (__hip_atomic_load(&flags[(j0 + tid) * 2 + cg],
                                     __ATOMIC_ACQUIRE, __HIP_MEMORY_SCOPE_AGENT) == 0u)
                __builtin_amdgcn_s_sleep(1);
        }
        __syncthreads();
        __threadfence();                       // invalidate stale lines before carry reads
        float4 v[16];
#pragma unroll
        for (int k = 0; k < 16; ++k)
            if (k < nb)
                v[k] = ((const float4*)(carry + (size_t)(j0 + k) * DIMN))[d4];
#pragma unroll
        for (int k = 0; k < 16; ++k)
            if (k < nb) {
                ha = fmaf(Fa, ha, v[k].x);
                hb = fmaf(Fb, hb, v[k].y);
                hc = fmaf(Fc, hc, v[k].z);
                hd = fmaf(Fd, hd, v[k].w);
            }
    }

    // 4. emit: x_mix[t] = loc[t] + f^(t+1) * h_in, as bf16
    ushort4* op = (ushort4*)(xmix + (size_t)c * CHUNK * DIMN) + d4;
    float pa = fa, pb = fb, pc = fc, pd = fd;
#pragma unroll
    for (int t = 0; t < CHUNK; ++t) {
        float oa = fmaf(pa, ha, loc[t][0]);
        float ob = fmaf(pb, hb, loc[t][1]);
        float oc = fmaf(pc, hc, loc[t][2]);
        float od = fmaf(pd, hd, loc[t][3]);
        ushort4 o; o.x = f2bf(oa); o.y = f2bf(ob); o.z = f2bf(oc); o.w = f2bf(od);
        op[(size_t)t * (DIMN / 4)] = o;
        pa *= fa; pb *= fb; pc *= fc; pd *= fd;
    }
}

// ---- GEMM: C[M][N] = A[M][K] * B[N][K]^T, bf16 in / fp32 out ----
// (R0 version, proven 67-68 us, MfmaUtil ~41%, 0 bank conflicts.)
// 128x256 block tile, BK=64, 4 waves, each wave 64x128 (4x8 of 16x16x32 MFMA).
__global__ __launch_bounds__(256, 2) void gemm_bt(
        const unsigned short* __restrict__ A,
        const unsigned short* __restrict__ B,
        float* __restrict__ C) {
    constexpr int N_ = DIMN, K_ = DIMN;
    constexpr int BK = 64;
    __shared__ __align__(16) unsigned short As[128 * BK];   // 16 KB
    __shared__ __align__(16) unsigned short Bs[256 * BK];   // 32 KB

    int tid  = threadIdx.x;
    int wave = tid >> 6;
    int lane = tid & 63;
    int quad = lane >> 4;
    int l16  = lane & 15;
    int tm = blockIdx.x, tn = blockIdx.y;
    int wm = wave >> 1, wn = wave & 1;

    f32x4 acc[4][8];
#pragma unroll
    for (int i = 0; i < 4; ++i)
#pragma unroll
        for (int j = 0; j < 8; ++j)
            acc[i][j] = (f32x4){0.f, 0.f, 0.f, 0.f};

    const unsigned short* aBase = A + (size_t)(tm * 128) * K_;
    const unsigned short* bBase = B + (size_t)(tn * 256) * K_;

    for (int k0 = 0; k0 < K_; k0 += BK) {
#pragma unroll
        for (int i = 0; i < 4; ++i) {
            int idx = i * 256 + tid;          // A: 1024 chunks
            int row = idx >> 3, slot = idx & 7;
            int cc = slot ^ (row & 7);
            __builtin_amdgcn_global_load_lds(
                (const __attribute__((address_space(1))) void*)(aBase + (size_t)row * K_ + k0 + cc * 8),
                (__attribute__((address_space(3))) void*)(As + idx * 8), 16, 0, 0);
        }
#pragma unroll
        for (int i = 0; i < 8; ++i) {
            int idx = i * 256 + tid;          // B: 2048 chunks
            int row = idx >> 3, slot = idx & 7;
            int cc = slot ^ (row & 7);
            __builtin_amdgcn_global_load_lds(
                (const __attribute__((address_space(1))) void*)(bBase + (size_t)row * K_ + k0 + cc * 8),
                (__attribute__((address_space(3))) void*)(Bs + idx * 8), 16, 0, 0);
        }
        __syncthreads();

#pragma unroll
        for (int kk = 0; kk < BK; kk += 32) {
            bf16x8 af[4], bg[8];
#pragma unroll
            for (int i = 0; i < 4; ++i) {
                int r = wm * 64 + i * 16 + l16;
                int c0 = (kk >> 3) + quad;
                af[i] = *(const bf16x8*)(As + r * BK + ((c0 ^ (r & 7)) << 3));
            }
#pragma unroll
            for (int j = 0; j < 8; ++j) {
                int r = wn * 128 + j * 16 + l16;
                int c0 = (kk >> 3) + quad;
                bg[j] = *(const bf16x8*)(Bs + r * BK + ((c0 ^ (r & 7)) << 3));
            }
#pragma unroll
            for (int i = 0; i < 4; ++i)
#pragma unroll
                for (int j = 0; j < 8; ++j)
                    acc[i][j] = __builtin_amdgcn_mfma_f32_16x16x32_bf16(af[i], bg[j], acc[i][j], 0, 0, 0);
        }
        __syncthreads();
    }

    // Epilogue: C/D layout col = lane&15, row = quad*4 + reg.
#pragma unroll
    for (int i = 0; i < 4; ++i) {
#pragma unroll
        for (int j = 0; j < 8; ++j) {
            int col = tn * 256 + wn * 128 + j * 16 + l16;
#pragma unroll
            for (int r = 0; r < 4; ++r) {
                int row = tm * 128 + wm * 64 + i * 16 + quad * 4 + r;
                C[(size_t)row * N_ + col] = acc[i][j][r];
            }
        }
    }
}

extern "C" void kernel_launch(void* const* d_in, const int* in_sizes, int n_in,
                              void* d_out, int out_size, void* d_ws, size_t ws_size,
                              hipStream_t stream) {
    const float* x   = (const float*)d_in[0];   // [L, D]
    const float* xml = (const float*)d_in[1];   // [D]
    const float* fp  = (const float*)d_in[2];   // [D]
    const float* W   = (const float*)d_in[3];   // [D, D]
    float* out = (float*)d_out;                 // [L, D] fp32

    unsigned short* xmix = (unsigned short*)d_ws;                                       // 32 MB
    unsigned short* Wb   = (unsigned short*)((char*)d_ws + (size_t)L_SEQ * DIMN * 2);   // 8 MB
    float* carry = (float*)((char*)d_ws + (size_t)L_SEQ * DIMN * 2
                                        + (size_t)DIMN * DIMN * 2);                     // 2 MB
    unsigned int* flags = (unsigned int*)((char*)d_ws + (size_t)L_SEQ * DIMN * 2
                                        + (size_t)DIMN * DIMN * 2
                                        + (size_t)NCHUNK * DIMN * 4);                   // 2 KB

    zeroflags<<<1, 256, 0, stream>>>(flags);
    scan1p<<<NSCAN + NWCONV, 256, 0, stream>>>(x, fp, xml, W, carry, flags, xmix, Wb);
    gemm_bt<<<dim3(L_SEQ / 128, DIMN / 256), 256, 0, stream>>>(xmix, Wb, out);
}

// Round 7
// 209.788 us; speedup vs baseline: 3.5589x; 3.5589x over previous
//
#include <hip/hip_runtime.h>

#define L_SEQ 8192
#define DIMN  2048
#define CHUNK 32
#define NCHUNK (L_SEQ / CHUNK)   // 256

typedef float  f32x4  __attribute__((ext_vector_type(4)));
typedef __bf16 bf16x8 __attribute__((ext_vector_type(8)));
typedef unsigned short u16x8 __attribute__((ext_vector_type(8)));

__device__ __forceinline__ unsigned short f2bf(float f) {
    unsigned int u = __float_as_uint(f);
    u += 0x7fffu + ((u >> 16) & 1u);          // round-to-nearest-even
    return (unsigned short)(u >> 16);
}

__device__ __forceinline__ float sigmoidf_(float v) {
    return 1.0f / (1.0f + __expf(-v));
}

// ---- W fp32 -> bf16 convert. Launched FIRST (R5: wconv right before gemm
// cost gemm ~6 us via cache state). ----
__global__ void wconv(const float* __restrict__ W, unsigned short* __restrict__ Wb) {
    int i = blockIdx.x * 256 + threadIdx.x;        // float4 index into W
    float4 v = ((const float4*)W)[i];
    ushort4 o;
    o.x = f2bf(v.x); o.y = f2bf(v.y); o.z = f2bf(v.z); o.w = f2bf(v.w);
    ((ushort4*)Wb)[i] = o;
}

// ---- Stage 1: local chunk scans, FULLY CONTIGUOUS streaming. ----
// Block = one whole chunk (32 rows x 2048 ch). Thread owns 8 ADJACENT channels
// (2x float4 = 32B/lane); a wave reads 2KB contiguous per row; block streams a
// contiguous 256KB slab of x in row order. This replaces the old pattern
// (1KB granule, 8KB power-of-two stride) suspected of capping BW at ~1 TB/s.
__global__ __launch_bounds__(256) void stage1(const float* __restrict__ x,
                                              const float* __restrict__ fp,
                                              float* __restrict__ carry) {
    const int c  = blockIdx.x;                 // chunk
    const int t2 = threadIdx.x * 2;            // float4 index of channel group
    float4 fA = ((const float4*)fp)[t2];
    float4 fB = ((const float4*)fp)[t2 + 1];
    float f0 = sigmoidf_(fA.x), f1 = sigmoidf_(fA.y), f2 = sigmoidf_(fA.z), f3 = sigmoidf_(fA.w);
    float f4_ = sigmoidf_(fB.x), f5 = sigmoidf_(fB.y), f6 = sigmoidf_(fB.z), f7 = sigmoidf_(fB.w);
    float g0 = 1.f - f0, g1 = 1.f - f1, g2 = 1.f - f2, g3 = 1.f - f3;
    float g4 = 1.f - f4_, g5 = 1.f - f5, g6 = 1.f - f6, g7 = 1.f - f7;
    float h0 = 0.f, h1 = 0.f, h2 = 0.f, h3 = 0.f, h4 = 0.f, h5 = 0.f, h6 = 0.f, h7 = 0.f;
    const float4* xp = (const float4*)(x + (size_t)c * CHUNK * DIMN) + t2;
#pragma unroll 4
    for (int t = 0; t < CHUNK; ++t) {
        float4 a = xp[(size_t)t * (DIMN / 4)];
        float4 b = xp[(size_t)t * (DIMN / 4) + 1];
        h0 = fmaf(f0, h0, g0 * a.x);
        h1 = fmaf(f1, h1, g1 * a.y);
        h2 = fmaf(f2, h2, g2 * a.z);
        h3 = fmaf(f3, h3, g3 * a.w);
        h4 = fmaf(f4_, h4, g4 * b.x);
        h5 = fmaf(f5, h5, g5 * b.y);
        h6 = fmaf(f6, h6, g6 * b.z);
        h7 = fmaf(f7, h7, g7 * b.w);
    }
    float4* cp = (float4*)(carry + (size_t)c * DIMN) + t2;
    cp[0] = (float4){h0, h1, h2, h3};
    cp[1] = (float4){h4, h5, h6, h7};
}

// ---- Stage 2: sequential prefix over 256 chunks, ALL carries in VGPRs ----
// (R5-proven: one wide-issue load burst, no serial memory round trips.)
__global__ __launch_bounds__(256) void carry_prefix(const float* __restrict__ fp,
                                                    const float* __restrict__ xml,
                                                    float* __restrict__ carry) {
    int d = blockIdx.x * 256 + threadIdx.x;        // one channel per lane
    float f = sigmoidf_(fp[d]);
    float fC = f;                                   // f^32 via 5 squarings
    fC *= fC; fC *= fC; fC *= fC; fC *= fC; fC *= fC;
    float v[NCHUNK];
#pragma unroll
    for (int c = 0; c < NCHUNK; ++c) v[c] = carry[(size_t)c * DIMN + d];
    float h = xml[d];
#pragma unroll
    for (int c = 0; c < NCHUNK; ++c) {
        carry[(size_t)c * DIMN + d] = h;            // h_in for chunk c
        h = fmaf(fC, h, v[c]);
    }
}

// ---- Stage 3: re-scan with correct h_in, streaming layout, emit bf16 ----
__global__ __launch_bounds__(256) void scan_apply(const float* __restrict__ x,
                                                  const float* __restrict__ fp,
                                                  const float* __restrict__ carry,
                                                  unsigned short* __restrict__ xmix) {
    const int c  = blockIdx.x;
    const int t2 = threadIdx.x * 2;
    float4 fA = ((const float4*)fp)[t2];
    float4 fB = ((const float4*)fp)[t2 + 1];
    float f0 = sigmoidf_(fA.x), f1 = sigmoidf_(fA.y), f2 = sigmoidf_(fA.z), f3 = sigmoidf_(fA.w);
    float f4_ = sigmoidf_(fB.x), f5 = sigmoidf_(fB.y), f6 = sigmoidf_(fB.z), f7 = sigmoidf_(fB.w);
    float g0 = 1.f - f0, g1 = 1.f - f1, g2 = 1.f - f2, g3 = 1.f - f3;
    float g4 = 1.f - f4_, g5 = 1.f - f5, g6 = 1.f - f6, g7 = 1.f - f7;
    const float4* hp = (const float4*)(carry + (size_t)c * DIMN) + t2;
    float4 hA = hp[0], hB = hp[1];
    float h0 = hA.x, h1 = hA.y, h2 = hA.z, h3 = hA.w;
    float h4 = hB.x, h5 = hB.y, h6 = hB.z, h7 = hB.w;
    const float4* xp = (const float4*)(x + (size_t)c * CHUNK * DIMN) + t2;
    u16x8* op = (u16x8*)(xmix + (size_t)c * CHUNK * DIMN) + threadIdx.x;
#pragma unroll 4
    for (int t = 0; t < CHUNK; ++t) {
        float4 a = xp[(size_t)t * (DIMN / 4)];
        float4 b = xp[(size_t)t * (DIMN / 4) + 1];
        h0 = fmaf(f0, h0, g0 * a.x);
        h1 = fmaf(f1, h1, g1 * a.y);
        h2 = fmaf(f2, h2, g2 * a.z);
        h3 = fmaf(f3, h3, g3 * a.w);
        h4 = fmaf(f4_, h4, g4 * b.x);
        h5 = fmaf(f5, h5, g5 * b.y);
        h6 = fmaf(f6, h6, g6 * b.z);
        h7 = fmaf(f7, h7, g7 * b.w);
        u16x8 o;
        o[0] = f2bf(h0); o[1] = f2bf(h1); o[2] = f2bf(h2); o[3] = f2bf(h3);
        o[4] = f2bf(h4); o[5] = f2bf(h5); o[6] = f2bf(h6); o[7] = f2bf(h7);
        op[(size_t)t * (DIMN / 8)] = o;
    }
}

// ---- GEMM: C[M][N] = A[M][K] * B[N][K]^T, bf16 in / fp32 out ----
// (R0 version, proven 67-68 us, MfmaUtil ~41%, 0 bank conflicts.)
// 128x256 block tile, BK=64, 4 waves, each wave 64x128 (4x8 of 16x16x32 MFMA).
__global__ __launch_bounds__(256, 2) void gemm_bt(
        const unsigned short* __restrict__ A,
        const unsigned short* __restrict__ B,
        float* __restrict__ C) {
    constexpr int N_ = DIMN, K_ = DIMN;
    constexpr int BK = 64;
    __shared__ __align__(16) unsigned short As[128 * BK];   // 16 KB
    __shared__ __align__(16) unsigned short Bs[256 * BK];   // 32 KB

    int tid  = threadIdx.x;
    int wave = tid >> 6;
    int lane = tid & 63;
    int quad = lane >> 4;
    int l16  = lane & 15;
    int tm = blockIdx.x, tn = blockIdx.y;
    int wm = wave >> 1, wn = wave & 1;

    f32x4 acc[4][8];
#pragma unroll
    for (int i = 0; i < 4; ++i)
#pragma unroll
        for (int j = 0; j < 8; ++j)
            acc[i][j] = (f32x4){0.f, 0.f, 0.f, 0.f};

    const unsigned short* aBase = A + (size_t)(tm * 128) * K_;
    const unsigned short* bBase = B + (size_t)(tn * 256) * K_;

    for (int k0 = 0; k0 < K_; k0 += BK) {
#pragma unroll
        for (int i = 0; i < 4; ++i) {
            int idx = i * 256 + tid;          // A: 1024 chunks
            int row = idx >> 3, slot = idx & 7;
            int cc = slot ^ (row & 7);
            __builtin_amdgcn_global_load_lds(
                (const __attribute__((address_space(1))) void*)(aBase + (size_t)row * K_ + k0 + cc * 8),
                (__attribute__((address_space(3))) void*)(As + idx * 8), 16, 0, 0);
        }
#pragma unroll
        for (int i = 0; i < 8; ++i) {
            int idx = i * 256 + tid;          // B: 2048 chunks
            int row = idx >> 3, slot = idx & 7;
            int cc = slot ^ (row & 7);
            __builtin_amdgcn_global_load_lds(
                (const __attribute__((address_space(1))) void*)(bBase + (size_t)row * K_ + k0 + cc * 8),
                (__attribute__((address_space(3))) void*)(Bs + idx * 8), 16, 0, 0);
        }
        __syncthreads();

#pragma unroll
        for (int kk = 0; kk < BK; kk += 32) {
            bf16x8 af[4], bg[8];
#pragma unroll
            for (int i = 0; i < 4; ++i) {
                int r = wm * 64 + i * 16 + l16;
                int c0 = (kk >> 3) + quad;
                af[i] = *(const bf16x8*)(As + r * BK + ((c0 ^ (r & 7)) << 3));
            }
#pragma unroll
            for (int j = 0; j < 8; ++j) {
                int r = wn * 128 + j * 16 + l16;
                int c0 = (kk >> 3) + quad;
                bg[j] = *(const bf16x8*)(Bs + r * BK + ((c0 ^ (r & 7)) << 3));
            }
#pragma unroll
            for (int i = 0; i < 4; ++i)
#pragma unroll
                for (int j = 0; j < 8; ++j)
                    acc[i][j] = __builtin_amdgcn_mfma_f32_16x16x32_bf16(af[i], bg[j], acc[i][j], 0, 0, 0);
        }
        __syncthreads();
    }

    // Epilogue: C/D layout col = lane&15, row = quad*4 + reg.
#pragma unroll
    for (int i = 0; i < 4; ++i) {
#pragma unroll
        for (int j = 0; j < 8; ++j) {
            int col = tn * 256 + wn * 128 + j * 16 + l16;
#pragma unroll
            for (int r = 0; r < 4; ++r) {
                int row = tm * 128 + wm * 64 + i * 16 + quad * 4 + r;
                C[(size_t)row * N_ + col] = acc[i][j][r];
            }
        }
    }
}

extern "C" void kernel_launch(void* const* d_in, const int* in_sizes, int n_in,
                              void* d_out, int out_size, void* d_ws, size_t ws_size,
                              hipStream_t stream) {
    const float* x   = (const float*)d_in[0];   // [L, D]
    const float* xml = (const float*)d_in[1];   // [D]
    const float* fp  = (const float*)d_in[2];   // [D]
    const float* W   = (const float*)d_in[3];   // [D, D]
    float* out = (float*)d_out;                 // [L, D] fp32

    unsigned short* xmix = (unsigned short*)d_ws;                                      // 32 MB
    unsigned short* Wb   = (unsigned short*)((char*)d_ws + (size_t)L_SEQ * DIMN * 2);  // 8 MB
    float* carry = (float*)((char*)d_ws + (size_t)L_SEQ * DIMN * 2 + (size_t)DIMN * DIMN * 2); // 2 MB

    wconv<<<DIMN * DIMN / 4 / 256, 256, 0, stream>>>(W, Wb);
    stage1<<<NCHUNK, 256, 0, stream>>>(x, fp, carry);
    carry_prefix<<<DIMN / 256, 256, 0, stream>>>(fp, xml, carry);
    scan_apply<<<NCHUNK, 256, 0, stream>>>(x, fp, carry, xmix);
    gemm_bt<<<dim3(L_SEQ / 128, DIMN / 256), 256, 0, stream>>>(xmix, Wb, out);
}